// Round 5
// baseline (30.270 us; speedup 1.0000x reference)
//
#include <hip/hip_runtime.h>

#define BUF     50
#define MAXK    10
#define NPAD    49        // BUF-1
#define BLK     256
#define HIDDEN  512
#define H4      128       // HIDDEN/4 float4 per row
#define SEQ     4096
#define PPB     256       // positions per block == block size: 1 pos/thread

typedef float v4f __attribute__((ext_vector_type(4)));

// ---------------------------------------------------------------------------
// Fused kernel, full-lane FD. Block = 256 threads = 256 positions; grid = 256
// blocks (1/CU). Phase 1: stage close[base-49 .. base+255] (305 floats) in
// LDS; EVERY thread computes the Higuchi FD of its own position (all 4 waves,
// all 64 lanes -> FD issue cost 1 wave/SIMD, ~1.4us chip-wide). Phase 2: all
// waves stream 256 rows x 512 floats as coalesced plain v4f stores, fd values
// hoisted to registers in chunks of 16.
// ---------------------------------------------------------------------------
__global__ __launch_bounds__(BLK) void fused_kernel(
    const float* __restrict__ x, const v4f* __restrict__ W4,
    const v4f* __restrict__ b4, v4f* __restrict__ out, int P) {
    __shared__ float sm_close[PPB + NPAD];  // 305
    __shared__ float sm_fd[PPB];

    const int base = blockIdx.x * PPB;
    const int tid = threadIdx.x;

    {   // stage close = x[:,:,3]; left edge of block 0 is zero-padded
        const int src = base - NPAD + tid;
        sm_close[tid] = (src >= 0) ? x[src * 8 + 3] : 0.0f;
        if (tid < NPAD) {
            // indices 256..304: src = base + 207 + tid, always in [0, P)
            sm_close[PPB + tid] = x[(base - NPAD + PPB + tid) * 8 + 3];
        }
    }
    __syncthreads();

    {   // Higuchi FD for position p = base + tid (one position per thread)
        float w[BUF];
#pragma unroll
        for (int j = 0; j < BUF; ++j) w[j] = sm_close[tid + j];

        const float logk_tab[MAXK] = {0.0f,        0.69314718f, 1.09861229f,
                                      1.38629436f, 1.60943791f, 1.79175947f,
                                      1.94591015f, 2.07944154f, 2.19722458f,
                                      2.30258509f};

        float Sw = 0.0f, Sx = 0.0f, Sy = 0.0f, Sxx = 0.0f, Sxy = 0.0f;
#pragma unroll
        for (int k = 1; k <= MAXK; ++k) {
            float acc = 0.0f;
#pragma unroll
            for (int m = 0; m < k; ++m) {
                const int Nm = (NPAD - m) / k + 1;  // len(arange(m, BUF, k))
                if (Nm >= 2) {
                    float len = 0.0f;
#pragma unroll
                    for (int i = 1; i < Nm; ++i)
                        len += fabsf(w[m + i * k] - w[m + (i - 1) * k]);
                    acc += len * ((float)NPAD / ((float)Nm * (float)k));
                }
            }
            const float lk = acc / (float)k;
            if (lk > 0.0f) {
                const float lg = logk_tab[k - 1];
                const float ly = __logf(fmaxf(lk, 1e-30f));
                Sw += 1.0f;
                Sx += lg;
                Sy += ly;
                Sxx += lg * lg;
                Sxy += lg * ly;
            }
        }
        const float denom = Sw * Sxx - Sx * Sx;
        const float slope =
            (fabsf(denom) > 1e-12f) ? (Sw * Sxy - Sx * Sy) / denom : 0.0f;
        float fd = (Sw > 1.0f) ? -slope : 0.0f;

        const int s = (base + tid) & (SEQ - 1);  // time mask: s < MAX_K -> 0
        if (s < MAXK) fd = 0.0f;
        sm_fd[tid] = fd;
    }
    __syncthreads();

    // Phase 2: 256 rows * 128 v4f = 32768 v4f per block, 128 per thread.
    const int h4 = tid & (H4 - 1);          // loop-invariant column block
    const int rbase = tid >> 7;             // 0 or 1
    const v4f Wv = W4[h4];
    const v4f bv = b4[h4];
    v4f* outb = out + (size_t)base * H4 + (size_t)rbase * H4 + h4;

    for (int c = 0; c < PPB / 32; ++c) {    // 8 chunks of 16 rows/thread
        float hreg[16];
#pragma unroll
        for (int i = 0; i < 16; ++i) hreg[i] = sm_fd[(c * 16 + i) * 2 + rbase];
#pragma unroll
        for (int i = 0; i < 16; ++i) {
            const float h = hreg[i];
            v4f o;
            o.x = fmaxf(fmaf(h, Wv.x, bv.x), 0.0f);
            o.y = fmaxf(fmaf(h, Wv.y, bv.y), 0.0f);
            o.z = fmaxf(fmaf(h, Wv.z, bv.z), 0.0f);
            o.w = fmaxf(fmaf(h, Wv.w, bv.w), 0.0f);
            outb[(size_t)(c * 16 + i) * 2 * H4] = o;
        }
    }
}

extern "C" void kernel_launch(void* const* d_in, const int* in_sizes, int n_in,
                              void* d_out, int out_size, void* d_ws,
                              size_t ws_size, hipStream_t stream) {
    const float* x = (const float*)d_in[0];   // (16, 4096, 8)
    const v4f* W4 = (const v4f*)d_in[1];      // (512,1) contiguous
    const v4f* b4 = (const v4f*)d_in[2];      // (512,)
    v4f* out = (v4f*)d_out;                   // (16, 4096, 512) fp32

    const int P = in_sizes[0] / 8;            // 65536 positions
    fused_kernel<<<P / PPB, BLK, 0, stream>>>(x, W4, b4, out, P);
}

// Round 6
// 29.393 us; speedup vs baseline: 1.0298x; 1.0298x over previous
//
#include <hip/hip_runtime.h>

#define BUF     50
#define MAXK    10
#define NPAD    49        // BUF-1
#define BLK     256
#define HIDDEN  512
#define H4      128       // HIDDEN/4 float4 per row
#define SEQ     4096
#define PPB     64        // positions per block: full wave 0, one pos/lane

typedef float v4f __attribute__((ext_vector_type(4)));

// ---------------------------------------------------------------------------
// Fused kernel, R4 overlap structure + full-wave FD.
// grid = 1024 blocks (4/CU, 16 waves/CU). Phase 1: stage close[base-49 ..
// base+63] (113 floats) in LDS; wave 0's 64 lanes each compute the Higuchi FD
// of one position (no half-empty waves -> FD issue cost at its 1.4us floor).
// Phase 2: all 4 waves stream 64 rows x 512 floats as coalesced plain v4f
// stores with fd values hoisted to registers.
// ---------------------------------------------------------------------------
__global__ __launch_bounds__(BLK) void fused_kernel(
    const float* __restrict__ x, const v4f* __restrict__ W4,
    const v4f* __restrict__ b4, v4f* __restrict__ out, int P) {
    __shared__ float sm_close[PPB + NPAD];  // 113
    __shared__ float sm_fd[PPB];

    const int base = blockIdx.x * PPB;
    const int tid = threadIdx.x;

    if (tid < PPB + NPAD) {  // stage close = x[:,:,3]; block 0 left edge = 0
        const int src = base - NPAD + tid;
        sm_close[tid] = (src >= 0) ? x[src * 8 + 3] : 0.0f;
    }
    __syncthreads();

    if (tid < PPB) {  // wave 0, all 64 lanes: FD of position base+tid
        float w[BUF];
#pragma unroll
        for (int j = 0; j < BUF; ++j) w[j] = sm_close[tid + j];

        const float logk_tab[MAXK] = {0.0f,        0.69314718f, 1.09861229f,
                                      1.38629436f, 1.60943791f, 1.79175947f,
                                      1.94591015f, 2.07944154f, 2.19722458f,
                                      2.30258509f};

        float Sw = 0.0f, Sx = 0.0f, Sy = 0.0f, Sxx = 0.0f, Sxy = 0.0f;
#pragma unroll
        for (int k = 1; k <= MAXK; ++k) {
            float acc = 0.0f;
#pragma unroll
            for (int m = 0; m < k; ++m) {
                const int Nm = (NPAD - m) / k + 1;  // len(arange(m, BUF, k))
                if (Nm >= 2) {
                    float len = 0.0f;
#pragma unroll
                    for (int i = 1; i < Nm; ++i)
                        len += fabsf(w[m + i * k] - w[m + (i - 1) * k]);
                    acc += len * ((float)NPAD / ((float)Nm * (float)k));
                }
            }
            const float lk = acc / (float)k;
            if (lk > 0.0f) {
                const float lg = logk_tab[k - 1];
                const float ly = __logf(fmaxf(lk, 1e-30f));
                Sw += 1.0f;
                Sx += lg;
                Sy += ly;
                Sxx += lg * lg;
                Sxy += lg * ly;
            }
        }
        const float denom = Sw * Sxx - Sx * Sx;
        const float slope =
            (fabsf(denom) > 1e-12f) ? (Sw * Sxy - Sx * Sy) / denom : 0.0f;
        float fd = (Sw > 1.0f) ? -slope : 0.0f;

        const int s = (base + tid) & (SEQ - 1);  // time mask: s < MAX_K -> 0
        if (s < MAXK) fd = 0.0f;
        sm_fd[tid] = fd;
    }
    __syncthreads();

    // Phase 2: 64 rows * 128 v4f = 8192 v4f per block, 32 per thread.
    const int h4 = tid & (H4 - 1);          // loop-invariant column block
    const int rbase = tid >> 7;             // 0 or 1
    const v4f Wv = W4[h4];
    const v4f bv = b4[h4];
    v4f* outb = out + (size_t)base * H4 + (size_t)rbase * H4 + h4;

#pragma unroll
    for (int c = 0; c < 2; ++c) {           // 2 chunks of 16 rows/thread
        float hreg[16];
#pragma unroll
        for (int i = 0; i < 16; ++i) hreg[i] = sm_fd[(c * 16 + i) * 2 + rbase];
#pragma unroll
        for (int i = 0; i < 16; ++i) {
            const float h = hreg[i];
            v4f o;
            o.x = fmaxf(fmaf(h, Wv.x, bv.x), 0.0f);
            o.y = fmaxf(fmaf(h, Wv.y, bv.y), 0.0f);
            o.z = fmaxf(fmaf(h, Wv.z, bv.z), 0.0f);
            o.w = fmaxf(fmaf(h, Wv.w, bv.w), 0.0f);
            outb[(size_t)(c * 16 + i) * 2 * H4] = o;
        }
    }
}

extern "C" void kernel_launch(void* const* d_in, const int* in_sizes, int n_in,
                              void* d_out, int out_size, void* d_ws,
                              size_t ws_size, hipStream_t stream) {
    const float* x = (const float*)d_in[0];   // (16, 4096, 8)
    const v4f* W4 = (const v4f*)d_in[1];      // (512,1) contiguous
    const v4f* b4 = (const v4f*)d_in[2];      // (512,)
    v4f* out = (v4f*)d_out;                   // (16, 4096, 512) fp32

    const int P = in_sizes[0] / 8;            // 65536 positions
    fused_kernel<<<P / PPB, BLK, 0, stream>>>(x, W4, b4, out, P);
}